// Round 5
// baseline (124.020 us; speedup 1.0000x reference)
//
#include <hip/hip_runtime.h>
#include <hip/hip_bf16.h>
#include <stdint.h>

#define LOG2E 1.4426950408889634f
#define LN2   0.6931471805599453f

typedef float f32x4 __attribute__((ext_vector_type(4)));
typedef short s16x8 __attribute__((ext_vector_type(8)));
typedef short s16x4 __attribute__((ext_vector_type(4)));
typedef uint32_t u32x4 __attribute__((ext_vector_type(4)));

__device__ inline float fexp2(float x) { return __builtin_amdgcn_exp2f(x); }
__device__ inline float frcp (float x) { return __builtin_amdgcn_rcpf(x); }
__device__ inline float flog2(float x) { return __builtin_amdgcn_logf(x); }
__device__ inline float ftanh(float x) {
  float e = fexp2(x * (2.0f * LOG2E));
  return 1.0f - 2.0f * frcp(e + 1.0f);
}
__device__ inline short f2bf(float x) {
  uint32_t u = __float_as_uint(x);
  uint32_t r = (u + 0x7fffu + ((u >> 16) & 1u)) >> 16;
  return (short)r;
}
__device__ inline float bf2f(short h) {
  return __uint_as_float(((uint32_t)(uint16_t)h) << 16);
}
__device__ inline uint32_t pack2bf(float a, float b) {
  __hip_bfloat162 t = __float22bfloat162_rn(make_float2(a, b));
  uint32_t u; __builtin_memcpy(&u, &t, 4);
  return u;
}

// ---------------------------------------------------------------------------
// Kernel P: expand adjacency -> byte mask 0x00/0xFF  [8][1024][1024] bytes
// Self-detects whether adj arrived as int32 (bool promoted) or uint8.
// ---------------------------------------------------------------------------
__global__ __launch_bounds__(256) void k_adjpack(
    const void* __restrict__ adj, uint32_t* __restrict__ adjm)
{
  __shared__ uint32_t smode[4];
  const uint32_t* w32 = (const uint32_t*)adj;
  uint32_t probe = w32[blockIdx.x * 256 + threadIdx.x];   // first 1 MB: safe both ways
  uint32_t any = (probe > 1u) ? 1u : 0u;
  for (int m = 1; m < 64; m <<= 1) any |= __shfl_xor(any, m, 64);
  if ((threadIdx.x & 63) == 0) smode[threadIdx.x >> 6] = any;
  __syncthreads();
  uint32_t bytemode = smode[0] | smode[1] | smode[2] | smode[3];

  int gid = blockIdx.x * 256 + threadIdx.x;   // 32-byte output chunk
  uint32_t o[8];
  if (bytemode) {
    const u32x4* a = (const u32x4*)((const uint8_t*)adj + (size_t)gid * 32);
    u32x4 q0 = a[0], q1 = a[1];
#pragma unroll
    for (int k = 0; k < 4; k++) { o[k] = q0[k] * 0xFFu; o[4 + k] = q1[k] * 0xFFu; }
  } else {
    const uint32_t* a32 = (const uint32_t*)adj + (size_t)gid * 32;
#pragma unroll
    for (int k = 0; k < 8; k++) {
      u32x4 q = *(const u32x4*)(a32 + 4 * k);
      o[k] = (q[0] | (q[1] << 8) | (q[2] << 16) | (q[3] << 24)) * 0xFFu;
    }
  }
  u32x4* dst = (u32x4*)(adjm + (size_t)gid * 8);
  dst[0] = (u32x4){o[0], o[1], o[2], o[3]};
  dst[1] = (u32x4){o[4], o[5], o[6], o[7]};
}

// ---------------------------------------------------------------------------
// Kernel W: fragment-arranged w hi/lo planes for both layers (once).
// ---------------------------------------------------------------------------
__global__ __launch_bounds__(256) void k_wprep(
    const float* __restrict__ w0, const float* __restrict__ w1,
    short* __restrict__ wf0h, short* __restrict__ wf0l,
    short* __restrict__ wf1h, short* __restrict__ wf1l)
{
  int t = blockIdx.x * 256 + threadIdx.x;   // 0..8191
  int layer = t >> 12;
  int r = t & 4095;
  int l = r & 63, slot = r >> 6;
  int l15 = l & 15, c = l >> 4;
  int KC  = layer ? 8 : 4;
  int FO  = layer ? 16 : 32;
  int FIN = layer ? 256 : 128;
  int ct  = layer ? (slot >> 3) : (slot >> 2);
  int kc  = layer ? (slot & 7)  : (slot & 3);
  int col = ct * 16 + l15;
  int h   = layer ? (col >> 4) : (col >> 5);
  int o   = col & (FO - 1);
  const float* wp = (layer ? w1 : w0) + (size_t)h * FIN * FO + o;
  short* dh = (layer ? wf1h : wf0h) + (size_t)r * 8;
  short* dl = (layer ? wf1l : wf0l) + (size_t)r * 8;
#pragma unroll
  for (int j = 0; j < 8; j++) {
    int k = kc * 32 + 4 * c + (j & 3) + ((j >> 2) << 4);
    float wv = wp[(size_t)k * FO];
    short hh = f2bf(wv);
    dh[j] = hh;
    dl[j] = f2bf(wv - bf2f(hh));
  }
}

// ---------------------------------------------------------------------------
// Kernel E: emb gather + concat -> xcb bf16 hi/lo planes [8192][128]
// ---------------------------------------------------------------------------
__global__ __launch_bounds__(256) void k_embcat(
    const float* __restrict__ x, const int* __restrict__ verts,
    const float* __restrict__ emb,
    short* __restrict__ xh, short* __restrict__ xl)
{
  int i = blockIdx.x * 256 + threadIdx.x;
  if (i >= 8192 * 64) return;
  int row = i >> 6;
  int c2  = (i & 63) * 2;
  float v0, v1;
  if (c2 < 64) {
    v0 = x[row * 64 + c2];
    v1 = x[row * 64 + c2 + 1];
  } else {
    int v = verts[row];
    v0 = emb[(size_t)v * 64 + (c2 - 64)];
    v1 = emb[(size_t)v * 64 + (c2 - 64) + 1];
  }
  short h0 = f2bf(v0), h1 = f2bf(v1);
  short l0 = f2bf(v0 - bf2f(h0)), l1 = f2bf(v1 - bf2f(h1));
  ((uint32_t*)xh)[i] = (uint32_t)(uint16_t)h0 | ((uint32_t)(uint16_t)h1 << 16);
  ((uint32_t*)xl)[i] = (uint32_t)(uint16_t)l0 | ((uint32_t)(uint16_t)l1 << 16);
}

// ---------------------------------------------------------------------------
// Kernel H: h_prime = xc @ w[h]  (split-bf16, w frags preloaded), tanh -> s,d
// hpb hi plane only, FRAGMENT-ARRANGED: [bh][mc(32)][ctl(CT)][lane(64)][8 bf16]
// ---------------------------------------------------------------------------
template<int FIN, int FO>
__global__ __launch_bounds__(256) void k_hprime(
    const short* __restrict__ xcbh, const short* __restrict__ xcbl,
    const short* __restrict__ wfh, const short* __restrict__ wfl,
    const float* __restrict__ a_src, const float* __restrict__ a_dst,
    short* __restrict__ hpbh,
    float* __restrict__ sp, float* __restrict__ dp)
{
  constexpr int CT  = FO / 16;
  constexpr int CTB = 8 * FO / 16;
  constexpr int CTW = CTB / 4;
  constexpr int KC  = FIN / 32;

  int blk = blockIdx.x;              // 512
  int b   = blk >> 6;
  int ntg = blk & 63;
  int tid = threadIdx.x;
  int w4  = tid >> 6;
  int l   = tid & 63;
  int l15 = l & 15, c = l >> 4;

  int row = ntg * 16 + l15;
  const short* arowh = xcbh + ((size_t)(b * 1024 + row)) * FIN;
  const short* arowl = xcbl + ((size_t)(b * 1024 + row)) * FIN;

  f32x4 acc[CTW];
#pragma unroll
  for (int i = 0; i < CTW; i++) acc[i] = (f32x4){0.f, 0.f, 0.f, 0.f};

  for (int kc = 0; kc < KC; ++kc) {
    s16x4 ah0 = *(const s16x4*)(arowh + kc * 32 + 4 * c);
    s16x4 ah1 = *(const s16x4*)(arowh + kc * 32 + 4 * c + 16);
    s16x4 al0 = *(const s16x4*)(arowl + kc * 32 + 4 * c);
    s16x4 al1 = *(const s16x4*)(arowl + kc * 32 + 4 * c + 16);
    s16x8 afh, afl;
#pragma unroll
    for (int j = 0; j < 4; j++) {
      afh[j] = ah0[j]; afh[4 + j] = ah1[j];
      afl[j] = al0[j]; afl[4 + j] = al1[j];
    }
#pragma unroll
    for (int i = 0; i < CTW; i++) {
      int ct = w4 * CTW + i;
      s16x8 bfh = *(const s16x8*)(wfh + ((size_t)(ct * KC + kc) * 64 + l) * 8);
      s16x8 bfl = *(const s16x8*)(wfl + ((size_t)(ct * KC + kc) * 64 + l) * 8);
      acc[i] = __builtin_amdgcn_mfma_f32_16x16x32_bf16(afh, bfh, acc[i], 0, 0, 0);
      acc[i] = __builtin_amdgcn_mfma_f32_16x16x32_bf16(afl, bfh, acc[i], 0, 0, 0);
      acc[i] = __builtin_amdgcn_mfma_f32_16x16x32_bf16(afh, bfl, acc[i], 0, 0, 0);
    }
  }

  float s_acc[CTW][4];
  float d_acc[CTW][4];
#pragma unroll
  for (int i = 0; i < CTW; i++) {
    int ct  = w4 * CTW + i;
    int col = ct * 16 + l15;
    int h = col / FO, o = col % FO;
    float asv = a_src[h * FO + o];
    float adv = a_dst[h * FO + o];
    s16x4 hbh;
#pragma unroll
    for (int r = 0; r < 4; r++) {
      float hp = acc[i][r];
      hbh[r] = f2bf(hp);
      float t = ftanh(hp);
      s_acc[i][r] = t * asv;
      d_acc[i][r] = t * adv;
    }
    int bh  = b * 8 + h;
    int ctl = o >> 4;
    size_t off = ((((size_t)(bh * 32 + (ntg >> 1))) * CT + ctl) * 64 + l) * 16 + (size_t)(ntg & 1) * 8;
    *(s16x4*)((char*)hpbh + off) = hbh;
  }

  constexpr int HW = (CTW * 16) / FO;
#pragma unroll
  for (int hh = 0; hh < HW; ++hh) {
#pragma unroll
    for (int r = 0; r < 4; r++) {
      float sv = 0.f, dv = 0.f;
#pragma unroll
      for (int i = hh * CT; i < (hh + 1) * CT; ++i) { sv += s_acc[i][r]; dv += d_acc[i][r]; }
      for (int m = 1; m < 16; m <<= 1) {
        sv += __shfl_xor(sv, m, 64);
        dv += __shfl_xor(dv, m, 64);
      }
      if (l15 == 0) {
        int ct0 = w4 * CTW + hh * CT;
        int h   = (ct0 * 16) / FO;
        int bh  = b * 8 + h;
        int rn  = ntg * 16 + 4 * c + r;
        sp[bh * 1024 + rn] = sv * LOG2E;
        dp[bh * 1024 + rn] = dv * LOG2E;
      }
    }
  }
}

// ---------------------------------------------------------------------------
// Kernel A: masked softmax(leaky(s+d)) @ h_prime.
//   exp2 hoisted: pv = max(cA*D[m], cB*E[m]); mask via v_perm byte-mask AND;
//   row sums via MFMA against all-ones B fragment (no shuffles).
//   XCD-swizzled: XCD x owns bh in [8x, 8x+8).
// ---------------------------------------------------------------------------
template<int CT, bool IS_L0>
__global__ __launch_bounds__(256) void k_attn(
    const float* __restrict__ sp, const float* __restrict__ dp,
    const short* __restrict__ hpbh,
    const uint8_t* __restrict__ adjm,
    const float* __restrict__ bias,
    void* __restrict__ outh, void* __restrict__ outl)
{
  __shared__ float Dl[1024];
  __shared__ float El[1024];
  __shared__ float red[4];

  int i0   = blockIdx.x;          // 1024
  int xcd  = i0 & 7, slot = i0 >> 3;
  int bh   = xcd * 8 + (slot >> 4);
  int rb   = (slot & 15) * 64;
  int b    = bh >> 3;
  int tid  = threadIdx.x;
  int w4   = tid >> 6, l = tid & 63, l15 = l & 15, c = l >> 4;

  const float* dsrc = dp + bh * 1024;
  float mxl = -1e30f;
  for (int i = tid; i < 1024; i += 256) {
    float v = dsrc[i];
    Dl[i] = fexp2(v);
    El[i] = fexp2(0.2f * v);
    mxl = fmaxf(mxl, v);
  }
  for (int m = 1; m < 64; m <<= 1) mxl = fmaxf(mxl, __shfl_xor(mxl, m, 64));
  if (l == 0) red[w4] = mxl;
  __syncthreads();
  float maxd = fmaxf(fmaxf(red[0], red[1]), fmaxf(red[2], red[3]));

  int n = rb + w4 * 16 + l15;
  float svn = sp[bh * 1024 + n];
  float su  = svn + maxd;
  float ub  = fmaxf(su, 0.2f * su);      // >= true row max (leaky monotone)
  float cA  = fexp2(svn - ub);
  float cB  = fexp2(0.2f * svn - ub);
  const uint8_t* arow = adjm + ((size_t)(b * 1024 + n)) * 1024;
  const short* hpbase = hpbh + (size_t)bh * 32 * CT * 512;

  f32x4 acc[CT];
#pragma unroll
  for (int i = 0; i < CT; i++) acc[i] = (f32x4){0.f, 0.f, 0.f, 0.f};
  f32x4 accp = (f32x4){0.f, 0.f, 0.f, 0.f};
  s16x8 ones;
#pragma unroll
  for (int j = 0; j < 8; j++) ones[j] = (short)0x3F80;   // bf16 1.0

#pragma unroll 2
  for (int mc = 0; mc < 32; ++mc) {
    s16x8 bfr[CT];
#pragma unroll
    for (int i = 0; i < CT; i++)
      bfr[i] = *(const s16x8*)(hpbase + ((size_t)(mc * CT + i) * 64 + l) * 8);

    uint32_t m0 = *(const uint32_t*)(arow + mc * 32 + 4 * c);
    uint32_t m1 = *(const uint32_t*)(arow + mc * 32 + 16 + 4 * c);
    f32x4 D0 = *(const f32x4*)&Dl[mc * 32 + 4 * c];
    f32x4 E0 = *(const f32x4*)&El[mc * 32 + 4 * c];
    f32x4 D1 = *(const f32x4*)&Dl[mc * 32 + 16 + 4 * c];
    f32x4 E1 = *(const f32x4*)&El[mc * 32 + 16 + 4 * c];

    float p[8];
#pragma unroll
    for (int j = 0; j < 4; j++) {
      p[j]     = fmaxf(cA * D0[j], cB * E0[j]);
      p[4 + j] = fmaxf(cA * D1[j], cB * E1[j]);
    }
    union { s16x8 s; uint32_t w[4]; } pu;
    pu.w[0] = pack2bf(p[0], p[1]) & __builtin_amdgcn_perm(0u, m0, 0x01010000u);
    pu.w[1] = pack2bf(p[2], p[3]) & __builtin_amdgcn_perm(0u, m0, 0x03030202u);
    pu.w[2] = pack2bf(p[4], p[5]) & __builtin_amdgcn_perm(0u, m1, 0x01010000u);
    pu.w[3] = pack2bf(p[6], p[7]) & __builtin_amdgcn_perm(0u, m1, 0x03030202u);

#pragma unroll
    for (int i = 0; i < CT; i++)
      acc[i] = __builtin_amdgcn_mfma_f32_16x16x32_bf16(pu.s, bfr[i], acc[i], 0, 0, 0);
    accp = __builtin_amdgcn_mfma_f32_16x16x32_bf16(pu.s, ones, accp, 0, 0, 0);
  }

#pragma unroll
  for (int r = 0; r < 4; r++) {
    float inv = frcp(accp[r]);            // row sum for row rb + w4*16 + 4c + r
    int rown  = rb + w4 * 16 + 4 * c + r;
#pragma unroll
    for (int i = 0; i < CT; i++) {
      float v = acc[i][r] * inv;
      int col = i * 16 + l15;
      int h   = bh & 7;
      if (IS_L0) {
        v += bias[col];
        v = v > 0.f ? v : fexp2(v * LOG2E) - 1.f;   // elu
        size_t idx = ((size_t)(b * 1024 + rown)) * 256 + h * 32 + col;
        short vh = f2bf(v);
        ((short*)outh)[idx] = vh;
        ((short*)outl)[idx] = f2bf(v - bf2f(vh));
      } else {
        ((float*)outh)[(((size_t)(b * 8 + h)) * 1024 + rown) * 16 + col] = v;
      }
    }
  }
}

// ---------------------------------------------------------------------------
// Kernel F: mean over heads + bias + log_softmax(16)
// ---------------------------------------------------------------------------
__global__ __launch_bounds__(256) void k_final(
    const float* __restrict__ out1, const float* __restrict__ b1,
    float* __restrict__ out)
{
  int idx = blockIdx.x * 256 + threadIdx.x;
  if (idx >= 8192) return;
  int b = idx >> 10, n = idx & 1023;
  float v[16];
#pragma unroll
  for (int o = 0; o < 16; o++) v[o] = 0.f;
  for (int h = 0; h < 8; h++) {
    const float* p = out1 + (((size_t)(b * 8 + h)) * 1024 + n) * 16;
#pragma unroll
    for (int o = 0; o < 16; o++) v[o] += p[o];
  }
  float mx = -1e30f;
#pragma unroll
  for (int o = 0; o < 16; o++) {
    v[o] = v[o] * 0.125f + b1[o];
    mx = fmaxf(mx, v[o]);
  }
  float s = 0.f;
#pragma unroll
  for (int o = 0; o < 16; o++) s += fexp2((v[o] - mx) * LOG2E);
  float lse = flog2(s) * LN2;
#pragma unroll
  for (int o = 0; o < 16; o++) out[(size_t)idx * 16 + o] = v[o] - mx - lse;
}

// ---------------------------------------------------------------------------
extern "C" void kernel_launch(void* const* d_in, const int* in_sizes, int n_in,
                              void* d_out, int out_size, void* d_ws, size_t ws_size,
                              hipStream_t stream) {
  const float*   x     = (const float*)d_in[0];
  const int*     verts = (const int*)d_in[1];
  const void*    adj   = (const void*)d_in[2];   // int32 or uint8 — auto-detected
  const float*   emb   = (const float*)d_in[3];
  const float*   w0    = (const float*)d_in[4];
  const float*   as0   = (const float*)d_in[5];
  const float*   ad0   = (const float*)d_in[6];
  const float*   b0    = (const float*)d_in[7];
  const float*   w1    = (const float*)d_in[8];
  const float*   as1   = (const float*)d_in[9];
  const float*   ad1   = (const float*)d_in[10];
  const float*   b1    = (const float*)d_in[11];

  char* ws = (char*)d_ws;
  const size_t MB = 1ull << 20;
  short* xcbh  = (short*)(ws);                         // 2 MB
  short* xcbl  = (short*)(ws + 2 * MB);                // 2 MB
  short* hpb0h = (short*)(ws + 4 * MB);                // 4 MB (dead after attn0)
  float* out1  = (float*)(ws + 4 * MB);                // 4 MB (reuses hpb0h)
  float* s0    = (float*)(ws + 8 * MB);                // 256 KB
  float* d0    = (float*)(ws + 8 * MB + 256 * 1024);   // 256 KB
  short* x1h   = (short*)(ws + 8 * MB + 512 * 1024);   // 4 MB
  short* x1l   = (short*)(ws + 12 * MB + 512 * 1024);  // 4 MB
  short* hpb1h = (short*)(ws + 16 * MB + 512 * 1024);  // 2 MB
  float* s1    = (float*)(ws + 18 * MB + 512 * 1024);  // 256 KB
  float* d1    = (float*)(ws + 18 * MB + 768 * 1024);  // 256 KB
  uint32_t* adjm = (uint32_t*)(ws + 19 * MB);          // 8 MB
  short* wf0h  = (short*)(ws + 27 * MB);               // 64 KB each
  short* wf0l  = (short*)(ws + 27 * MB + 64 * 1024);
  short* wf1h  = (short*)(ws + 27 * MB + 128 * 1024);
  short* wf1l  = (short*)(ws + 27 * MB + 192 * 1024);  // ends 27.25 MB
  float* out   = (float*)d_out;

  k_adjpack<<<1024, 256, 0, stream>>>(adj, adjm);
  k_wprep<<<32, 256, 0, stream>>>(w0, w1, wf0h, wf0l, wf1h, wf1l);
  k_embcat<<<2048, 256, 0, stream>>>(x, verts, emb, xcbh, xcbl);
  k_hprime<128, 32><<<512, 256, 0, stream>>>(xcbh, xcbl, wf0h, wf0l, as0, ad0, hpb0h, s0, d0);
  k_attn<2, true><<<1024, 256, 0, stream>>>(s0, d0, hpb0h, (const uint8_t*)adjm, b0, (void*)x1h, (void*)x1l);
  k_hprime<256, 16><<<512, 256, 0, stream>>>(x1h, x1l, wf1h, wf1l, as1, ad1, hpb1h, s1, d1);
  k_attn<1, false><<<1024, 256, 0, stream>>>(s1, d1, hpb1h, (const uint8_t*)adjm, b1, (void*)out1, nullptr);
  k_final<<<32, 256, 0, stream>>>(out1, b1, out);
}

// Round 6
// 122.904 us; speedup vs baseline: 1.0091x; 1.0091x over previous
//
#include <hip/hip_runtime.h>
#include <hip/hip_bf16.h>
#include <stdint.h>

#define LOG2E 1.4426950408889634f
#define LN2   0.6931471805599453f

typedef float f32x4 __attribute__((ext_vector_type(4)));
typedef short s16x8 __attribute__((ext_vector_type(8)));
typedef short s16x4 __attribute__((ext_vector_type(4)));
typedef uint32_t u32x4 __attribute__((ext_vector_type(4)));

__device__ inline float fexp2(float x) { return __builtin_amdgcn_exp2f(x); }
__device__ inline float frcp (float x) { return __builtin_amdgcn_rcpf(x); }
__device__ inline float flog2(float x) { return __builtin_amdgcn_logf(x); }
__device__ inline float ftanh(float x) {
  float e = fexp2(x * (2.0f * LOG2E));
  return 1.0f - 2.0f * frcp(e + 1.0f);
}
__device__ inline short f2bf(float x) {
  uint32_t u = __float_as_uint(x);
  uint32_t r = (u + 0x7fffu + ((u >> 16) & 1u)) >> 16;
  return (short)r;
}
__device__ inline float bf2f(short h) {
  return __uint_as_float(((uint32_t)(uint16_t)h) << 16);
}
__device__ inline uint32_t pack2bf(float a, float b) {
  __hip_bfloat162 t = __float22bfloat162_rn(make_float2(a, b));
  uint32_t u; __builtin_memcpy(&u, &t, 4);
  return u;
}

// ---------------------------------------------------------------------------
// Kernel P: expand adjacency -> byte mask 0x00/0xFF  [8][1024][1024] bytes
// Self-detects whether adj arrived as int32 (bool promoted) or uint8.
// ---------------------------------------------------------------------------
__global__ __launch_bounds__(256) void k_adjpack(
    const void* __restrict__ adj, uint32_t* __restrict__ adjm)
{
  __shared__ uint32_t smode[4];
  const uint32_t* w32 = (const uint32_t*)adj;
  uint32_t probe = w32[blockIdx.x * 256 + threadIdx.x];   // first 1 MB: safe both ways
  uint32_t any = (probe > 1u) ? 1u : 0u;
  for (int m = 1; m < 64; m <<= 1) any |= __shfl_xor(any, m, 64);
  if ((threadIdx.x & 63) == 0) smode[threadIdx.x >> 6] = any;
  __syncthreads();
  uint32_t bytemode = smode[0] | smode[1] | smode[2] | smode[3];

  int gid = blockIdx.x * 256 + threadIdx.x;   // 32-byte output chunk
  uint32_t o[8];
  if (bytemode) {
    const u32x4* a = (const u32x4*)((const uint8_t*)adj + (size_t)gid * 32);
    u32x4 q0 = a[0], q1 = a[1];
#pragma unroll
    for (int k = 0; k < 4; k++) { o[k] = q0[k] * 0xFFu; o[4 + k] = q1[k] * 0xFFu; }
  } else {
    const uint32_t* a32 = (const uint32_t*)adj + (size_t)gid * 32;
#pragma unroll
    for (int k = 0; k < 8; k++) {
      u32x4 q = *(const u32x4*)(a32 + 4 * k);
      o[k] = (q[0] | (q[1] << 8) | (q[2] << 16) | (q[3] << 24)) * 0xFFu;
    }
  }
  u32x4* dst = (u32x4*)(adjm + (size_t)gid * 8);
  dst[0] = (u32x4){o[0], o[1], o[2], o[3]};
  dst[1] = (u32x4){o[4], o[5], o[6], o[7]};
}

// ---------------------------------------------------------------------------
// Kernel W: fragment-arranged w hi/lo planes for both layers (once).
// ---------------------------------------------------------------------------
__global__ __launch_bounds__(256) void k_wprep(
    const float* __restrict__ w0, const float* __restrict__ w1,
    short* __restrict__ wf0h, short* __restrict__ wf0l,
    short* __restrict__ wf1h, short* __restrict__ wf1l)
{
  int t = blockIdx.x * 256 + threadIdx.x;   // 0..8191
  int layer = t >> 12;
  int r = t & 4095;
  int l = r & 63, slot = r >> 6;
  int l15 = l & 15, c = l >> 4;
  int KC  = layer ? 8 : 4;
  int FO  = layer ? 16 : 32;
  int FIN = layer ? 256 : 128;
  int ct  = layer ? (slot >> 3) : (slot >> 2);
  int kc  = layer ? (slot & 7)  : (slot & 3);
  int col = ct * 16 + l15;
  int h   = layer ? (col >> 4) : (col >> 5);
  int o   = col & (FO - 1);
  const float* wp = (layer ? w1 : w0) + (size_t)h * FIN * FO + o;
  short* dh = (layer ? wf1h : wf0h) + (size_t)r * 8;
  short* dl = (layer ? wf1l : wf0l) + (size_t)r * 8;
#pragma unroll
  for (int j = 0; j < 8; j++) {
    int k = kc * 32 + 4 * c + (j & 3) + ((j >> 2) << 4);
    float wv = wp[(size_t)k * FO];
    short hh = f2bf(wv);
    dh[j] = hh;
    dl[j] = f2bf(wv - bf2f(hh));
  }
}

// ---------------------------------------------------------------------------
// Kernel E: emb gather + concat -> xcb bf16 hi/lo planes [8192][128]
// ---------------------------------------------------------------------------
__global__ __launch_bounds__(256) void k_embcat(
    const float* __restrict__ x, const int* __restrict__ verts,
    const float* __restrict__ emb,
    short* __restrict__ xh, short* __restrict__ xl)
{
  int i = blockIdx.x * 256 + threadIdx.x;
  if (i >= 8192 * 64) return;
  int row = i >> 6;
  int c2  = (i & 63) * 2;
  float v0, v1;
  if (c2 < 64) {
    v0 = x[row * 64 + c2];
    v1 = x[row * 64 + c2 + 1];
  } else {
    int v = verts[row];
    v0 = emb[(size_t)v * 64 + (c2 - 64)];
    v1 = emb[(size_t)v * 64 + (c2 - 64) + 1];
  }
  short h0 = f2bf(v0), h1 = f2bf(v1);
  short l0 = f2bf(v0 - bf2f(h0)), l1 = f2bf(v1 - bf2f(h1));
  ((uint32_t*)xh)[i] = (uint32_t)(uint16_t)h0 | ((uint32_t)(uint16_t)h1 << 16);
  ((uint32_t*)xl)[i] = (uint32_t)(uint16_t)l0 | ((uint32_t)(uint16_t)l1 << 16);
}

// ---------------------------------------------------------------------------
// Kernel H: h_prime = xc @ w[h]  (split-bf16, w frags preloaded), tanh -> s,d
// hpb hi plane only, FRAGMENT-ARRANGED: [bh][mc(32)][ctl(CT)][lane(64)][8 bf16]
// ---------------------------------------------------------------------------
template<int FIN, int FO>
__global__ __launch_bounds__(256) void k_hprime(
    const short* __restrict__ xcbh, const short* __restrict__ xcbl,
    const short* __restrict__ wfh, const short* __restrict__ wfl,
    const float* __restrict__ a_src, const float* __restrict__ a_dst,
    short* __restrict__ hpbh,
    float* __restrict__ sp, float* __restrict__ dp)
{
  constexpr int CT  = FO / 16;
  constexpr int CTB = 8 * FO / 16;
  constexpr int CTW = CTB / 4;
  constexpr int KC  = FIN / 32;

  int blk = blockIdx.x;              // 512
  int b   = blk >> 6;
  int ntg = blk & 63;
  int tid = threadIdx.x;
  int w4  = tid >> 6;
  int l   = tid & 63;
  int l15 = l & 15, c = l >> 4;

  int row = ntg * 16 + l15;
  const short* arowh = xcbh + ((size_t)(b * 1024 + row)) * FIN;
  const short* arowl = xcbl + ((size_t)(b * 1024 + row)) * FIN;

  f32x4 acc[CTW];
#pragma unroll
  for (int i = 0; i < CTW; i++) acc[i] = (f32x4){0.f, 0.f, 0.f, 0.f};

  for (int kc = 0; kc < KC; ++kc) {
    s16x4 ah0 = *(const s16x4*)(arowh + kc * 32 + 4 * c);
    s16x4 ah1 = *(const s16x4*)(arowh + kc * 32 + 4 * c + 16);
    s16x4 al0 = *(const s16x4*)(arowl + kc * 32 + 4 * c);
    s16x4 al1 = *(const s16x4*)(arowl + kc * 32 + 4 * c + 16);
    s16x8 afh, afl;
#pragma unroll
    for (int j = 0; j < 4; j++) {
      afh[j] = ah0[j]; afh[4 + j] = ah1[j];
      afl[j] = al0[j]; afl[4 + j] = al1[j];
    }
#pragma unroll
    for (int i = 0; i < CTW; i++) {
      int ct = w4 * CTW + i;
      s16x8 bfh = *(const s16x8*)(wfh + ((size_t)(ct * KC + kc) * 64 + l) * 8);
      s16x8 bfl = *(const s16x8*)(wfl + ((size_t)(ct * KC + kc) * 64 + l) * 8);
      acc[i] = __builtin_amdgcn_mfma_f32_16x16x32_bf16(afh, bfh, acc[i], 0, 0, 0);
      acc[i] = __builtin_amdgcn_mfma_f32_16x16x32_bf16(afl, bfh, acc[i], 0, 0, 0);
      acc[i] = __builtin_amdgcn_mfma_f32_16x16x32_bf16(afh, bfl, acc[i], 0, 0, 0);
    }
  }

  float s_acc[CTW][4];
  float d_acc[CTW][4];
#pragma unroll
  for (int i = 0; i < CTW; i++) {
    int ct  = w4 * CTW + i;
    int col = ct * 16 + l15;
    int h = col / FO, o = col % FO;
    float asv = a_src[h * FO + o];
    float adv = a_dst[h * FO + o];
    s16x4 hbh;
#pragma unroll
    for (int r = 0; r < 4; r++) {
      float hp = acc[i][r];
      hbh[r] = f2bf(hp);
      float t = ftanh(hp);
      s_acc[i][r] = t * asv;
      d_acc[i][r] = t * adv;
    }
    int bh  = b * 8 + h;
    int ctl = o >> 4;
    size_t off = ((((size_t)(bh * 32 + (ntg >> 1))) * CT + ctl) * 64 + l) * 16 + (size_t)(ntg & 1) * 8;
    *(s16x4*)((char*)hpbh + off) = hbh;
  }

  constexpr int HW = (CTW * 16) / FO;
#pragma unroll
  for (int hh = 0; hh < HW; ++hh) {
#pragma unroll
    for (int r = 0; r < 4; r++) {
      float sv = 0.f, dv = 0.f;
#pragma unroll
      for (int i = hh * CT; i < (hh + 1) * CT; ++i) { sv += s_acc[i][r]; dv += d_acc[i][r]; }
      for (int m = 1; m < 16; m <<= 1) {
        sv += __shfl_xor(sv, m, 64);
        dv += __shfl_xor(dv, m, 64);
      }
      if (l15 == 0) {
        int ct0 = w4 * CTW + hh * CT;
        int h   = (ct0 * 16) / FO;
        int bh  = b * 8 + h;
        int rn  = ntg * 16 + 4 * c + r;
        sp[bh * 1024 + rn] = sv * LOG2E;
        dp[bh * 1024 + rn] = dv * LOG2E;
      }
    }
  }
}

// ---------------------------------------------------------------------------
// Kernel A: masked softmax(leaky(s+d)) @ h_prime.
//   512 threads / 8 waves: wave = (row-tile r16, mc-half). Each wave does 16
//   pipelined iterations (dist-1 reg staging of adj + hpb); halves pair-reduce
//   acc/accp via LDS. Row sums via MFMA vs all-ones. XCD-swizzled.
// ---------------------------------------------------------------------------
template<int CT, bool IS_L0>
__global__ __launch_bounds__(512, 8) void k_attn(
    const float* __restrict__ sp, const float* __restrict__ dp,
    const short* __restrict__ hpbh,
    const uint8_t* __restrict__ adjm,
    const float* __restrict__ bias,
    void* __restrict__ outh, void* __restrict__ outl)
{
  __shared__ float Dl[1024];
  __shared__ float El[1024];
  __shared__ float red[8];
  __shared__ float racc[4][(CT + 1) * 4][64];

  int i0   = blockIdx.x;          // 1024
  int xcd  = i0 & 7, slot = i0 >> 3;
  int bh   = xcd * 8 + (slot >> 4);
  int rb   = (slot & 15) * 64;
  int b    = bh >> 3;
  int tid  = threadIdx.x;
  int wid  = tid >> 6;            // 0..7
  int r16  = wid >> 1;            // row tile
  int half = wid & 1;             // mc half
  int l = tid & 63, l15 = l & 15, c = l >> 4;

  const float* dsrc = dp + bh * 1024;
  float mxl = -1e30f;
  for (int i = tid; i < 1024; i += 512) {
    float v = dsrc[i];
    Dl[i] = fexp2(v);
    El[i] = fexp2(0.2f * v);
    mxl = fmaxf(mxl, v);
  }
  for (int m = 1; m < 64; m <<= 1) mxl = fmaxf(mxl, __shfl_xor(mxl, m, 64));
  if (l == 0) red[wid] = mxl;
  __syncthreads();
  float maxd = red[0];
#pragma unroll
  for (int i = 1; i < 8; i++) maxd = fmaxf(maxd, red[i]);

  int n = rb + r16 * 16 + l15;
  float svn = sp[bh * 1024 + n];
  float su  = svn + maxd;
  float ub  = fmaxf(su, 0.2f * su);      // >= true row max (leaky monotone)
  float cA  = fexp2(svn - ub);
  float cB  = fexp2(0.2f * svn - ub);
  const uint8_t* arow = adjm + ((size_t)(b * 1024 + n)) * 1024;
  const short* hpbase = hpbh + (size_t)bh * 32 * CT * 512;

  f32x4 acc[CT];
#pragma unroll
  for (int i = 0; i < CT; i++) acc[i] = (f32x4){0.f, 0.f, 0.f, 0.f};
  f32x4 accp = (f32x4){0.f, 0.f, 0.f, 0.f};
  s16x8 ones;
#pragma unroll
  for (int j = 0; j < 8; j++) ones[j] = (short)0x3F80;   // bf16 1.0

  const int mcBeg = half * 16;
  // distance-1 staging
  uint32_t nm0 = *(const uint32_t*)(arow + mcBeg * 32 + 4 * c);
  uint32_t nm1 = *(const uint32_t*)(arow + mcBeg * 32 + 16 + 4 * c);
  s16x8 nb[CT];
#pragma unroll
  for (int i = 0; i < CT; i++)
    nb[i] = *(const s16x8*)(hpbase + ((size_t)(mcBeg * CT + i) * 64 + l) * 8);

  for (int t = 0; t < 16; ++t) {
    int mc = mcBeg + t;
    uint32_t m0 = nm0, m1 = nm1;
    s16x8 cb[CT];
#pragma unroll
    for (int i = 0; i < CT; i++) cb[i] = nb[i];
    if (t < 15) {
      int mcn = mc + 1;
      nm0 = *(const uint32_t*)(arow + mcn * 32 + 4 * c);
      nm1 = *(const uint32_t*)(arow + mcn * 32 + 16 + 4 * c);
#pragma unroll
      for (int i = 0; i < CT; i++)
        nb[i] = *(const s16x8*)(hpbase + ((size_t)(mcn * CT + i) * 64 + l) * 8);
    }

    f32x4 D0 = *(const f32x4*)&Dl[mc * 32 + 4 * c];
    f32x4 E0 = *(const f32x4*)&El[mc * 32 + 4 * c];
    f32x4 D1 = *(const f32x4*)&Dl[mc * 32 + 16 + 4 * c];
    f32x4 E1 = *(const f32x4*)&El[mc * 32 + 16 + 4 * c];

    float p[8];
#pragma unroll
    for (int j = 0; j < 4; j++) {
      p[j]     = fmaxf(cA * D0[j], cB * E0[j]);
      p[4 + j] = fmaxf(cA * D1[j], cB * E1[j]);
    }
    union { s16x8 s; uint32_t w[4]; } pu;
    pu.w[0] = pack2bf(p[0], p[1]) & __builtin_amdgcn_perm(0u, m0, 0x01010000u);
    pu.w[1] = pack2bf(p[2], p[3]) & __builtin_amdgcn_perm(0u, m0, 0x03030202u);
    pu.w[2] = pack2bf(p[4], p[5]) & __builtin_amdgcn_perm(0u, m1, 0x01010000u);
    pu.w[3] = pack2bf(p[6], p[7]) & __builtin_amdgcn_perm(0u, m1, 0x03030202u);

#pragma unroll
    for (int i = 0; i < CT; i++)
      acc[i] = __builtin_amdgcn_mfma_f32_16x16x32_bf16(pu.s, cb[i], acc[i], 0, 0, 0);
    accp = __builtin_amdgcn_mfma_f32_16x16x32_bf16(pu.s, ones, accp, 0, 0, 0);
  }

  // pair-reduce the two mc-halves
  if (half == 1) {
#pragma unroll
    for (int i = 0; i < CT; i++)
#pragma unroll
      for (int r = 0; r < 4; r++) racc[r16][i * 4 + r][l] = acc[i][r];
#pragma unroll
    for (int r = 0; r < 4; r++) racc[r16][CT * 4 + r][l] = accp[r];
  }
  __syncthreads();
  if (half == 0) {
#pragma unroll
    for (int i = 0; i < CT; i++)
#pragma unroll
      for (int r = 0; r < 4; r++) acc[i][r] += racc[r16][i * 4 + r][l];
#pragma unroll
    for (int r = 0; r < 4; r++) {
      float rs  = accp[r] + racc[r16][CT * 4 + r][l];
      float inv = frcp(rs);
      int rown  = rb + r16 * 16 + 4 * c + r;
#pragma unroll
      for (int i = 0; i < CT; i++) {
        float v = acc[i][r] * inv;
        int col = i * 16 + l15;
        int h   = bh & 7;
        if (IS_L0) {
          v += bias[col];
          v = v > 0.f ? v : fexp2(v * LOG2E) - 1.f;   // elu
          size_t idx = ((size_t)(b * 1024 + rown)) * 256 + h * 32 + col;
          short vh = f2bf(v);
          ((short*)outh)[idx] = vh;
          ((short*)outl)[idx] = f2bf(v - bf2f(vh));
        } else {
          ((float*)outh)[(((size_t)(b * 8 + h)) * 1024 + rown) * 16 + col] = v;
        }
      }
    }
  }
}

// ---------------------------------------------------------------------------
// Kernel F: mean over heads + bias + log_softmax(16)
// ---------------------------------------------------------------------------
__global__ __launch_bounds__(256) void k_final(
    const float* __restrict__ out1, const float* __restrict__ b1,
    float* __restrict__ out)
{
  int idx = blockIdx.x * 256 + threadIdx.x;
  if (idx >= 8192) return;
  int b = idx >> 10, n = idx & 1023;
  float v[16];
#pragma unroll
  for (int o = 0; o < 16; o++) v[o] = 0.f;
  for (int h = 0; h < 8; h++) {
    const float* p = out1 + (((size_t)(b * 8 + h)) * 1024 + n) * 16;
#pragma unroll
    for (int o = 0; o < 16; o++) v[o] += p[o];
  }
  float mx = -1e30f;
#pragma unroll
  for (int o = 0; o < 16; o++) {
    v[o] = v[o] * 0.125f + b1[o];
    mx = fmaxf(mx, v[o]);
  }
  float s = 0.f;
#pragma unroll
  for (int o = 0; o < 16; o++) s += fexp2((v[o] - mx) * LOG2E);
  float lse = flog2(s) * LN2;
#pragma unroll
  for (int o = 0; o < 16; o++) out[(size_t)idx * 16 + o] = v[o] - mx - lse;
}

// ---------------------------------------------------------------------------
extern "C" void kernel_launch(void* const* d_in, const int* in_sizes, int n_in,
                              void* d_out, int out_size, void* d_ws, size_t ws_size,
                              hipStream_t stream) {
  const float*   x     = (const float*)d_in[0];
  const int*     verts = (const int*)d_in[1];
  const void*    adj   = (const void*)d_in[2];   // int32 or uint8 — auto-detected
  const float*   emb   = (const float*)d_in[3];
  const float*   w0    = (const float*)d_in[4];
  const float*   as0   = (const float*)d_in[5];
  const float*   ad0   = (const float*)d_in[6];
  const float*   b0    = (const float*)d_in[7];
  const float*   w1    = (const float*)d_in[8];
  const float*   as1   = (const float*)d_in[9];
  const float*   ad1   = (const float*)d_in[10];
  const float*   b1    = (const float*)d_in[11];

  char* ws = (char*)d_ws;
  const size_t MB = 1ull << 20;
  short* xcbh  = (short*)(ws);                         // 2 MB
  short* xcbl  = (short*)(ws + 2 * MB);                // 2 MB
  short* hpb0h = (short*)(ws + 4 * MB);                // 4 MB (dead after attn0)
  float* out1  = (float*)(ws + 4 * MB);                // 4 MB (reuses hpb0h)
  float* s0    = (float*)(ws + 8 * MB);                // 256 KB
  float* d0    = (float*)(ws + 8 * MB + 256 * 1024);   // 256 KB
  short* x1h   = (short*)(ws + 8 * MB + 512 * 1024);   // 4 MB
  short* x1l   = (short*)(ws + 12 * MB + 512 * 1024);  // 4 MB
  short* hpb1h = (short*)(ws + 16 * MB + 512 * 1024);  // 2 MB
  float* s1    = (float*)(ws + 18 * MB + 512 * 1024);  // 256 KB
  float* d1    = (float*)(ws + 18 * MB + 768 * 1024);  // 256 KB
  uint32_t* adjm = (uint32_t*)(ws + 19 * MB);          // 8 MB
  short* wf0h  = (short*)(ws + 27 * MB);               // 64 KB each
  short* wf0l  = (short*)(ws + 27 * MB + 64 * 1024);
  short* wf1h  = (short*)(ws + 27 * MB + 128 * 1024);
  short* wf1l  = (short*)(ws + 27 * MB + 192 * 1024);  // ends 27.25 MB
  float* out   = (float*)d_out;

  k_adjpack<<<1024, 256, 0, stream>>>(adj, adjm);
  k_wprep<<<32, 256, 0, stream>>>(w0, w1, wf0h, wf0l, wf1h, wf1l);
  k_embcat<<<2048, 256, 0, stream>>>(x, verts, emb, xcbh, xcbl);
  k_hprime<128, 32><<<512, 256, 0, stream>>>(xcbh, xcbl, wf0h, wf0l, as0, ad0, hpb0h, s0, d0);
  k_attn<2, true><<<1024, 512, 0, stream>>>(s0, d0, hpb0h, (const uint8_t*)adjm, b0, (void*)x1h, (void*)x1l);
  k_hprime<256, 16><<<512, 256, 0, stream>>>(x1h, x1l, wf1h, wf1l, as1, ad1, hpb1h, s1, d1);
  k_attn<1, false><<<1024, 512, 0, stream>>>(s1, d1, hpb1h, (const uint8_t*)adjm, b1, (void*)out1, nullptr);
  k_final<<<32, 256, 0, stream>>>(out1, b1, out);
}

// Round 7
// 91.397 us; speedup vs baseline: 1.3569x; 1.3447x over previous
//
#include <hip/hip_runtime.h>
#include <hip/hip_bf16.h>
#include <stdint.h>

#define LOG2E 1.4426950408889634f
#define LN2   0.6931471805599453f

typedef float f32x4 __attribute__((ext_vector_type(4)));
typedef short s16x8 __attribute__((ext_vector_type(8)));
typedef short s16x4 __attribute__((ext_vector_type(4)));
typedef uint32_t u32x4 __attribute__((ext_vector_type(4)));
typedef uint32_t u32x2 __attribute__((ext_vector_type(2)));

__device__ inline float fexp2(float x) { return __builtin_amdgcn_exp2f(x); }
__device__ inline float frcp (float x) { return __builtin_amdgcn_rcpf(x); }
__device__ inline float flog2(float x) { return __builtin_amdgcn_logf(x); }
__device__ inline float ftanh(float x) {
  float e = fexp2(x * (2.0f * LOG2E));
  return 1.0f - 2.0f * frcp(e + 1.0f);
}
__device__ inline short f2bf(float x) {
  uint32_t u = __float_as_uint(x);
  uint32_t r = (u + 0x7fffu + ((u >> 16) & 1u)) >> 16;
  return (short)r;
}
__device__ inline float bf2f(short h) {
  return __uint_as_float(((uint32_t)(uint16_t)h) << 16);
}
__device__ inline uint32_t pack2bf(float a, float b) {
  __hip_bfloat162 t = __float22bfloat162_rn(make_float2(a, b));
  uint32_t u; __builtin_memcpy(&u, &t, 4);
  return u;
}

// ---------------------------------------------------------------------------
// Kernel P: permuted adjacency tiles, byte-mask 0x00/0xFF.
// adjt[((b*64+nt16)*32+mc)*128 + lane*2 + {0,1}]:
//   lane=(c*16+l15) -> dword0 = mask bytes (n=nt16*16+l15, m=mc*32+4c..+3)
//                      dword1 = same at m+16.
// In k_attn a wave reads its whole 512B tile with ONE coalesced dwordx2.
// Self-detects int32 vs uint8 storage of the bool input.
// ---------------------------------------------------------------------------
__global__ __launch_bounds__(256) void k_adjperm(
    const void* __restrict__ adj, uint32_t* __restrict__ adjt)
{
  __shared__ uint32_t smode[4];
  const uint32_t* w32 = (const uint32_t*)adj;
  uint32_t probe = w32[blockIdx.x * 256 + threadIdx.x];   // < 256 KB: safe both modes
  uint32_t any = (probe > 1u) ? 1u : 0u;
  for (int m = 1; m < 64; m <<= 1) any |= __shfl_xor(any, m, 64);
  if ((threadIdx.x & 63) == 0) smode[threadIdx.x >> 6] = any;
  __syncthreads();
  uint32_t bytemode = smode[0] | smode[1] | smode[2] | smode[3];

  int t  = blockIdx.x * 256 + threadIdx.x;   // 65536 threads = (b, nt16, mc, c)
  int c  = t & 3;
  int mc = (t >> 2) & 31;
  int nt = (t >> 7) & 63;
  int b  = t >> 13;
  uint32_t* dst = adjt + (((size_t)(b * 64 + nt) * 32 + mc) * 128) + c * 32;

  if (bytemode) {
#pragma unroll 4
    for (int l15 = 0; l15 < 16; ++l15) {
      const uint8_t* src = (const uint8_t*)adj +
          ((size_t)(b * 1024 + nt * 16 + l15) * 1024 + mc * 32 + 4 * c);
      uint32_t lo = *(const uint32_t*)src;
      uint32_t hi = *(const uint32_t*)(src + 16);
      dst[2 * l15]     = lo * 0xFFu;   // per-byte 0/1 -> 0x00/0xFF (no carry: 0xFF*1 < 256)
      dst[2 * l15 + 1] = hi * 0xFFu;
    }
  } else {
#pragma unroll 4
    for (int l15 = 0; l15 < 16; ++l15) {
      const uint32_t* src = (const uint32_t*)adj +
          ((size_t)(b * 1024 + nt * 16 + l15) * 1024 + mc * 32 + 4 * c);
      u32x4 qa = *(const u32x4*)src;
      u32x4 qb = *(const u32x4*)(src + 16);
      dst[2 * l15] = (qa[0] ? 0xFFu : 0u) | (qa[1] ? 0xFF00u : 0u) |
                     (qa[2] ? 0xFF0000u : 0u) | (qa[3] ? 0xFF000000u : 0u);
      dst[2 * l15 + 1] = (qb[0] ? 0xFFu : 0u) | (qb[1] ? 0xFF00u : 0u) |
                         (qb[2] ? 0xFF0000u : 0u) | (qb[3] ? 0xFF000000u : 0u);
    }
  }
}

// ---------------------------------------------------------------------------
// Kernel D: per-bh packed DE table + exact dmax.
//   DEp[bh][m] = (bf16(2^d[m]) << 16) | bf16(2^(0.2 d[m]))   (d pre-scaled by log2e)
// ---------------------------------------------------------------------------
__global__ __launch_bounds__(256) void k_prep(
    const float* __restrict__ dp, uint32_t* __restrict__ DEp,
    float* __restrict__ dmax)
{
  __shared__ float red[4];
  __shared__ float bmax;
  int bh = blockIdx.x, tid = threadIdx.x;
  f32x4 d = *(const f32x4*)&dp[bh * 1024 + tid * 4];
  float mx = fmaxf(fmaxf(d[0], d[1]), fmaxf(d[2], d[3]));
  for (int m = 1; m < 64; m <<= 1) mx = fmaxf(mx, __shfl_xor(mx, m, 64));
  if ((tid & 63) == 0) red[tid >> 6] = mx;
  __syncthreads();
  if (tid == 0) {
    float v = fmaxf(fmaxf(red[0], red[1]), fmaxf(red[2], red[3]));
    bmax = v;
    dmax[bh] = v;
  }
  __syncthreads();
  u32x4 o;
#pragma unroll
  for (int j = 0; j < 4; j++) {
    float D = fexp2(d[j]);
    float E = fexp2(0.2f * d[j]);
    o[j] = ((uint32_t)(uint16_t)f2bf(D) << 16) | (uint32_t)(uint16_t)f2bf(E);
  }
  *(u32x4*)&DEp[bh * 1024 + tid * 4] = o;
}

// ---------------------------------------------------------------------------
// Kernel W: fragment-arranged w hi/lo planes for both layers (once).
// ---------------------------------------------------------------------------
__global__ __launch_bounds__(256) void k_wprep(
    const float* __restrict__ w0, const float* __restrict__ w1,
    short* __restrict__ wf0h, short* __restrict__ wf0l,
    short* __restrict__ wf1h, short* __restrict__ wf1l)
{
  int t = blockIdx.x * 256 + threadIdx.x;   // 0..8191
  int layer = t >> 12;
  int r = t & 4095;
  int l = r & 63, slot = r >> 6;
  int l15 = l & 15, c = l >> 4;
  int KC  = layer ? 8 : 4;
  int FO  = layer ? 16 : 32;
  int FIN = layer ? 256 : 128;
  int ct  = layer ? (slot >> 3) : (slot >> 2);
  int kc  = layer ? (slot & 7)  : (slot & 3);
  int col = ct * 16 + l15;
  int h   = layer ? (col >> 4) : (col >> 5);
  int o   = col & (FO - 1);
  const float* wp = (layer ? w1 : w0) + (size_t)h * FIN * FO + o;
  short* dh = (layer ? wf1h : wf0h) + (size_t)r * 8;
  short* dl = (layer ? wf1l : wf0l) + (size_t)r * 8;
#pragma unroll
  for (int j = 0; j < 8; j++) {
    int k = kc * 32 + 4 * c + (j & 3) + ((j >> 2) << 4);
    float wv = wp[(size_t)k * FO];
    short hh = f2bf(wv);
    dh[j] = hh;
    dl[j] = f2bf(wv - bf2f(hh));
  }
}

// ---------------------------------------------------------------------------
// Kernel E: emb gather + concat -> xcb bf16 hi/lo planes [8192][128]
// ---------------------------------------------------------------------------
__global__ __launch_bounds__(256) void k_embcat(
    const float* __restrict__ x, const int* __restrict__ verts,
    const float* __restrict__ emb,
    short* __restrict__ xh, short* __restrict__ xl)
{
  int i = blockIdx.x * 256 + threadIdx.x;
  if (i >= 8192 * 64) return;
  int row = i >> 6;
  int c2  = (i & 63) * 2;
  float v0, v1;
  if (c2 < 64) {
    v0 = x[row * 64 + c2];
    v1 = x[row * 64 + c2 + 1];
  } else {
    int v = verts[row];
    v0 = emb[(size_t)v * 64 + (c2 - 64)];
    v1 = emb[(size_t)v * 64 + (c2 - 64) + 1];
  }
  short h0 = f2bf(v0), h1 = f2bf(v1);
  short l0 = f2bf(v0 - bf2f(h0)), l1 = f2bf(v1 - bf2f(h1));
  ((uint32_t*)xh)[i] = (uint32_t)(uint16_t)h0 | ((uint32_t)(uint16_t)h1 << 16);
  ((uint32_t*)xl)[i] = (uint32_t)(uint16_t)l0 | ((uint32_t)(uint16_t)l1 << 16);
}

// ---------------------------------------------------------------------------
// Kernel H: h_prime = xc @ w[h]  (split-bf16, w frags preloaded), tanh -> s,d
// hpb hi plane FRAGMENT-ARRANGED: [bh][mc(32)][ctl(CT)][lane(64)][8 bf16]
// ---------------------------------------------------------------------------
template<int FIN, int FO>
__global__ __launch_bounds__(256) void k_hprime(
    const short* __restrict__ xcbh, const short* __restrict__ xcbl,
    const short* __restrict__ wfh, const short* __restrict__ wfl,
    const float* __restrict__ a_src, const float* __restrict__ a_dst,
    short* __restrict__ hpbh,
    float* __restrict__ sp, float* __restrict__ dp)
{
  constexpr int CT  = FO / 16;
  constexpr int CTB = 8 * FO / 16;
  constexpr int CTW = CTB / 4;
  constexpr int KC  = FIN / 32;

  int blk = blockIdx.x;              // 512
  int b   = blk >> 6;
  int ntg = blk & 63;
  int tid = threadIdx.x;
  int w4  = tid >> 6;
  int l   = tid & 63;
  int l15 = l & 15, c = l >> 4;

  int row = ntg * 16 + l15;
  const short* arowh = xcbh + ((size_t)(b * 1024 + row)) * FIN;
  const short* arowl = xcbl + ((size_t)(b * 1024 + row)) * FIN;

  f32x4 acc[CTW];
#pragma unroll
  for (int i = 0; i < CTW; i++) acc[i] = (f32x4){0.f, 0.f, 0.f, 0.f};

  for (int kc = 0; kc < KC; ++kc) {
    s16x4 ah0 = *(const s16x4*)(arowh + kc * 32 + 4 * c);
    s16x4 ah1 = *(const s16x4*)(arowh + kc * 32 + 4 * c + 16);
    s16x4 al0 = *(const s16x4*)(arowl + kc * 32 + 4 * c);
    s16x4 al1 = *(const s16x4*)(arowl + kc * 32 + 4 * c + 16);
    s16x8 afh, afl;
#pragma unroll
    for (int j = 0; j < 4; j++) {
      afh[j] = ah0[j]; afh[4 + j] = ah1[j];
      afl[j] = al0[j]; afl[4 + j] = al1[j];
    }
#pragma unroll
    for (int i = 0; i < CTW; i++) {
      int ct = w4 * CTW + i;
      s16x8 bfh = *(const s16x8*)(wfh + ((size_t)(ct * KC + kc) * 64 + l) * 8);
      s16x8 bfl = *(const s16x8*)(wfl + ((size_t)(ct * KC + kc) * 64 + l) * 8);
      acc[i] = __builtin_amdgcn_mfma_f32_16x16x32_bf16(afh, bfh, acc[i], 0, 0, 0);
      acc[i] = __builtin_amdgcn_mfma_f32_16x16x32_bf16(afl, bfh, acc[i], 0, 0, 0);
      acc[i] = __builtin_amdgcn_mfma_f32_16x16x32_bf16(afh, bfl, acc[i], 0, 0, 0);
    }
  }

  float s_acc[CTW][4];
  float d_acc[CTW][4];
#pragma unroll
  for (int i = 0; i < CTW; i++) {
    int ct  = w4 * CTW + i;
    int col = ct * 16 + l15;
    int h = col / FO, o = col % FO;
    float asv = a_src[h * FO + o];
    float adv = a_dst[h * FO + o];
    s16x4 hbh;
#pragma unroll
    for (int r = 0; r < 4; r++) {
      float hp = acc[i][r];
      hbh[r] = f2bf(hp);
      float t = ftanh(hp);
      s_acc[i][r] = t * asv;
      d_acc[i][r] = t * adv;
    }
    int bh  = b * 8 + h;
    int ctl = o >> 4;
    size_t off = ((((size_t)(bh * 32 + (ntg >> 1))) * CT + ctl) * 64 + l) * 16 + (size_t)(ntg & 1) * 8;
    *(s16x4*)((char*)hpbh + off) = hbh;
  }

  constexpr int HW = (CTW * 16) / FO;
#pragma unroll
  for (int hh = 0; hh < HW; ++hh) {
#pragma unroll
    for (int r = 0; r < 4; r++) {
      float sv = 0.f, dv = 0.f;
#pragma unroll
      for (int i = hh * CT; i < (hh + 1) * CT; ++i) { sv += s_acc[i][r]; dv += d_acc[i][r]; }
      for (int m = 1; m < 16; m <<= 1) {
        sv += __shfl_xor(sv, m, 64);
        dv += __shfl_xor(dv, m, 64);
      }
      if (l15 == 0) {
        int ct0 = w4 * CTW + hh * CT;
        int h   = (ct0 * 16) / FO;
        int bh  = b * 8 + h;
        int rn  = ntg * 16 + 4 * c + r;
        sp[bh * 1024 + rn] = sv * LOG2E;
        dp[bh * 1024 + rn] = dv * LOG2E;
      }
    }
  }
}

// ---------------------------------------------------------------------------
// Kernel A: masked softmax(leaky(s+d)) @ h_prime.
//   adj: ONE coalesced dwordx2 per iter (permuted tiles).
//   D/E: bf16-packed u32 table in LDS, 2 ds_read_b128 per iter.
//   Row sums via MFMA vs all-ones. 8 waves: (row-tile, mc-half). XCD-swizzled.
// ---------------------------------------------------------------------------
template<int CT, bool IS_L0>
__global__ __launch_bounds__(512, 8) void k_attn(
    const float* __restrict__ sp, const uint32_t* __restrict__ DEp,
    const float* __restrict__ dmax,
    const short* __restrict__ hpbh,
    const uint32_t* __restrict__ adjt,
    const float* __restrict__ bias,
    void* __restrict__ outh, void* __restrict__ outl)
{
  __shared__ uint32_t DEl[1024];
  __shared__ float racc[4][(CT + 1) * 4][64];

  int i0   = blockIdx.x;          // 1024
  int xcd  = i0 & 7, slot = i0 >> 3;
  int bh   = xcd * 8 + (slot >> 4);
  int rb   = (slot & 15) * 64;
  int b    = bh >> 3;
  int tid  = threadIdx.x;
  int wid  = tid >> 6;            // 0..7
  int r16  = wid >> 1;            // row tile
  int half = wid & 1;             // mc half
  int l = tid & 63, l15 = l & 15, c = l >> 4;

  for (int i = tid; i < 1024; i += 512) DEl[i] = DEp[bh * 1024 + i];

  float maxd = dmax[bh];
  int n = rb + r16 * 16 + l15;
  float svn = sp[bh * 1024 + n];
  float su  = svn + maxd;
  float ub  = fmaxf(su, 0.2f * su);      // >= true row max (leaky monotone)
  float cA  = fexp2(svn - ub);
  float cB  = fexp2(0.2f * svn - ub);
  const short* hpbase = hpbh + (size_t)bh * 32 * CT * 512;
  const uint32_t* atile = adjt + ((size_t)(b * 64 + (rb >> 4) + r16) * 32) * 128 + l * 2;

  __syncthreads();

  f32x4 acc[CT];
#pragma unroll
  for (int i = 0; i < CT; i++) acc[i] = (f32x4){0.f, 0.f, 0.f, 0.f};
  f32x4 accp = (f32x4){0.f, 0.f, 0.f, 0.f};
  s16x8 ones;
#pragma unroll
  for (int j = 0; j < 8; j++) ones[j] = (short)0x3F80;   // bf16 1.0

  const int mcBeg = half * 16;
  // distance-1 staging
  u32x2 nam = *(const u32x2*)(atile + (size_t)mcBeg * 128);
  s16x8 nb[CT];
#pragma unroll
  for (int i = 0; i < CT; i++)
    nb[i] = *(const s16x8*)(hpbase + ((size_t)(mcBeg * CT + i) * 64 + l) * 8);

  for (int t = 0; t < 16; ++t) {
    int mc = mcBeg + t;
    u32x2 am = nam;
    s16x8 cb[CT];
#pragma unroll
    for (int i = 0; i < CT; i++) cb[i] = nb[i];
    if (t < 15) {
      int mcn = mc + 1;
      nam = *(const u32x2*)(atile + (size_t)mcn * 128);
#pragma unroll
      for (int i = 0; i < CT; i++)
        nb[i] = *(const s16x8*)(hpbase + ((size_t)(mcn * CT + i) * 64 + l) * 8);
    }

    u32x4 delo = *(const u32x4*)&DEl[mc * 32 + 4 * c];
    u32x4 dehi = *(const u32x4*)&DEl[mc * 32 + 16 + 4 * c];

    float p[8];
#pragma unroll
    for (int j = 0; j < 4; j++) {
      float D0 = __uint_as_float(delo[j] & 0xFFFF0000u);
      float E0 = __uint_as_float(delo[j] << 16);
      p[j] = fmaxf(cA * D0, cB * E0);
      float D1 = __uint_as_float(dehi[j] & 0xFFFF0000u);
      float E1 = __uint_as_float(dehi[j] << 16);
      p[4 + j] = fmaxf(cA * D1, cB * E1);
    }
    union { s16x8 s; uint32_t w[4]; } pu;
    pu.w[0] = pack2bf(p[0], p[1]) & __builtin_amdgcn_perm(0u, am[0], 0x01010000u);
    pu.w[1] = pack2bf(p[2], p[3]) & __builtin_amdgcn_perm(0u, am[0], 0x03030202u);
    pu.w[2] = pack2bf(p[4], p[5]) & __builtin_amdgcn_perm(0u, am[1], 0x01010000u);
    pu.w[3] = pack2bf(p[6], p[7]) & __builtin_amdgcn_perm(0u, am[1], 0x03030202u);

#pragma unroll
    for (int i = 0; i < CT; i++)
      acc[i] = __builtin_amdgcn_mfma_f32_16x16x32_bf16(pu.s, cb[i], acc[i], 0, 0, 0);
    accp = __builtin_amdgcn_mfma_f32_16x16x32_bf16(pu.s, ones, accp, 0, 0, 0);
  }

  // pair-reduce the two mc-halves
  if (half == 1) {
#pragma unroll
    for (int i = 0; i < CT; i++)
#pragma unroll
      for (int r = 0; r < 4; r++) racc[r16][i * 4 + r][l] = acc[i][r];
#pragma unroll
    for (int r = 0; r < 4; r++) racc[r16][CT * 4 + r][l] = accp[r];
  }
  __syncthreads();
  if (half == 0) {
#pragma unroll
    for (int i = 0; i < CT; i++)
#pragma unroll
      for (int r = 0; r < 4; r++) acc[i][r] += racc[r16][i * 4 + r][l];
#pragma unroll
    for (int r = 0; r < 4; r++) {
      float rs  = accp[r] + racc[r16][CT * 4 + r][l];
      float inv = frcp(rs);
      int rown  = rb + r16 * 16 + 4 * c + r;
#pragma unroll
      for (int i = 0; i < CT; i++) {
        float v = acc[i][r] * inv;
        int col = i * 16 + l15;
        int h   = bh & 7;
        if (IS_L0) {
          v += bias[col];
          v = v > 0.f ? v : fexp2(v * LOG2E) - 1.f;   // elu
          size_t idx = ((size_t)(b * 1024 + rown)) * 256 + h * 32 + col;
          short vh = f2bf(v);
          ((short*)outh)[idx] = vh;
          ((short*)outl)[idx] = f2bf(v - bf2f(vh));
        } else {
          ((float*)outh)[(((size_t)(b * 8 + h)) * 1024 + rown) * 16 + col] = v;
        }
      }
    }
  }
}

// ---------------------------------------------------------------------------
// Kernel F: mean over heads + bias + log_softmax(16)
// ---------------------------------------------------------------------------
__global__ __launch_bounds__(256) void k_final(
    const float* __restrict__ out1, const float* __restrict__ b1,
    float* __restrict__ out)
{
  int idx = blockIdx.x * 256 + threadIdx.x;
  if (idx >= 8192) return;
  int b = idx >> 10, n = idx & 1023;
  float v[16];
#pragma unroll
  for (int o = 0; o < 16; o++) v[o] = 0.f;
  for (int h = 0; h < 8; h++) {
    const float* p = out1 + (((size_t)(b * 8 + h)) * 1024 + n) * 16;
#pragma unroll
    for (int o = 0; o < 16; o++) v[o] += p[o];
  }
  float mx = -1e30f;
#pragma unroll
  for (int o = 0; o < 16; o++) {
    v[o] = v[o] * 0.125f + b1[o];
    mx = fmaxf(mx, v[o]);
  }
  float s = 0.f;
#pragma unroll
  for (int o = 0; o < 16; o++) s += fexp2((v[o] - mx) * LOG2E);
  float lse = flog2(s) * LN2;
#pragma unroll
  for (int o = 0; o < 16; o++) out[(size_t)idx * 16 + o] = v[o] - mx - lse;
}

// ---------------------------------------------------------------------------
extern "C" void kernel_launch(void* const* d_in, const int* in_sizes, int n_in,
                              void* d_out, int out_size, void* d_ws, size_t ws_size,
                              hipStream_t stream) {
  const float*   x     = (const float*)d_in[0];
  const int*     verts = (const int*)d_in[1];
  const void*    adj   = (const void*)d_in[2];   // int32 or uint8 — auto-detected
  const float*   emb   = (const float*)d_in[3];
  const float*   w0    = (const float*)d_in[4];
  const float*   as0   = (const float*)d_in[5];
  const float*   ad0   = (const float*)d_in[6];
  const float*   b0    = (const float*)d_in[7];
  const float*   w1    = (const float*)d_in[8];
  const float*   as1   = (const float*)d_in[9];
  const float*   ad1   = (const float*)d_in[10];
  const float*   b1    = (const float*)d_in[11];

  char* ws = (char*)d_ws;
  const size_t MB = 1ull << 20;
  short* xcbh  = (short*)(ws);                         // 2 MB
  short* xcbl  = (short*)(ws + 2 * MB);                // 2 MB
  short* hpb0h = (short*)(ws + 4 * MB);                // 4 MB (dead after attn0)
  float* out1  = (float*)(ws + 4 * MB);                // 4 MB (reuses hpb0h)
  float* s0    = (float*)(ws + 8 * MB);                // 256 KB
  float* d0    = (float*)(ws + 8 * MB + 256 * 1024);   // 256 KB
  short* x1h   = (short*)(ws + 8 * MB + 512 * 1024);   // 4 MB
  short* x1l   = (short*)(ws + 12 * MB + 512 * 1024);  // 4 MB
  short* hpb1h = (short*)(ws + 16 * MB + 512 * 1024);  // 2 MB
  float* s1    = (float*)(ws + 18 * MB + 512 * 1024);  // 256 KB
  float* d1    = (float*)(ws + 18 * MB + 768 * 1024);  // 256 KB
  uint32_t* adjt = (uint32_t*)(ws + 19 * MB);          // 8 MB
  short* wf0h  = (short*)(ws + 27 * MB);               // 64 KB each
  short* wf0l  = (short*)(ws + 27 * MB + 64 * 1024);
  short* wf1h  = (short*)(ws + 27 * MB + 128 * 1024);
  short* wf1l  = (short*)(ws + 27 * MB + 192 * 1024);
  uint32_t* DEp  = (uint32_t*)(ws + 27 * MB + 256 * 1024);  // 256 KB
  float*    dmax = (float*)(ws + 27 * MB + 512 * 1024);     // 256 B (ends ~27.5 MB)
  float* out   = (float*)d_out;

  k_adjperm<<<256, 256, 0, stream>>>(adj, adjt);
  k_wprep<<<32, 256, 0, stream>>>(w0, w1, wf0h, wf0l, wf1h, wf1l);
  k_embcat<<<2048, 256, 0, stream>>>(x, verts, emb, xcbh, xcbl);
  k_hprime<128, 32><<<512, 256, 0, stream>>>(xcbh, xcbl, wf0h, wf0l, as0, ad0, hpb0h, s0, d0);
  k_prep<<<64, 256, 0, stream>>>(d0, DEp, dmax);
  k_attn<2, true><<<1024, 512, 0, stream>>>(s0, DEp, dmax, hpb0h, adjt, b0, (void*)x1h, (void*)x1l);
  k_hprime<256, 16><<<512, 256, 0, stream>>>(x1h, x1l, wf1h, wf1l, as1, ad1, hpb1h, s1, d1);
  k_prep<<<64, 256, 0, stream>>>(d1, DEp, dmax);
  k_attn<1, false><<<1024, 512, 0, stream>>>(s1, DEp, dmax, hpb1h, adjt, b1, (void*)out1, nullptr);
  k_final<<<32, 256, 0, stream>>>(out1, b1, out);
}

// Round 9
// 81.106 us; speedup vs baseline: 1.5291x; 1.1269x over previous
//
#include <hip/hip_runtime.h>
#include <hip/hip_bf16.h>
#include <stdint.h>

#define LOG2E 1.4426950408889634f
#define LN2   0.6931471805599453f

typedef float f32x4 __attribute__((ext_vector_type(4)));
typedef short s16x8 __attribute__((ext_vector_type(8)));
typedef short s16x4 __attribute__((ext_vector_type(4)));
typedef _Float16 f16x8 __attribute__((ext_vector_type(8)));
typedef _Float16 h2x2 __attribute__((ext_vector_type(2)));
typedef uint32_t u32x4 __attribute__((ext_vector_type(4)));
typedef uint32_t u32x2 __attribute__((ext_vector_type(2)));

__device__ inline float fexp2(float x) { return __builtin_amdgcn_exp2f(x); }
__device__ inline float frcp (float x) { return __builtin_amdgcn_rcpf(x); }
__device__ inline float flog2(float x) { return __builtin_amdgcn_logf(x); }
__device__ inline float ftanh(float x) {
  float e = fexp2(x * (2.0f * LOG2E));
  return 1.0f - 2.0f * frcp(e + 1.0f);
}
__device__ inline short f2bf(float x) {
  uint32_t u = __float_as_uint(x);
  uint32_t r = (u + 0x7fffu + ((u >> 16) & 1u)) >> 16;
  return (short)r;
}
__device__ inline float bf2f(short h) {
  return __uint_as_float(((uint32_t)(uint16_t)h) << 16);
}
__device__ inline uint32_t h2bits(h2x2 v) {
  uint32_t u; __builtin_memcpy(&u, &v, 4); return u;
}
__device__ inline h2x2 bits2h(uint32_t u) {
  h2x2 v; __builtin_memcpy(&v, &u, 4); return v;
}

// ---------------------------------------------------------------------------
// Kernel P: permuted adjacency tiles, byte-mask 0x00/0xFF.
// adjt[((b*64+nt16)*32+mc)*128 + lane*2 + {0,1}]: one coalesced dwordx2/iter.
// Self-detects int32 vs uint8 storage of the bool input.
// ---------------------------------------------------------------------------
__global__ __launch_bounds__(256) void k_adjperm(
    const void* __restrict__ adj, uint32_t* __restrict__ adjt)
{
  __shared__ uint32_t smode[4];
  const uint32_t* w32 = (const uint32_t*)adj;
  uint32_t probe = w32[blockIdx.x * 256 + threadIdx.x];   // < 256 KB: safe both modes
  uint32_t any = (probe > 1u) ? 1u : 0u;
  for (int m = 1; m < 64; m <<= 1) any |= __shfl_xor(any, m, 64);
  if ((threadIdx.x & 63) == 0) smode[threadIdx.x >> 6] = any;
  __syncthreads();
  uint32_t bytemode = smode[0] | smode[1] | smode[2] | smode[3];

  int t  = blockIdx.x * 256 + threadIdx.x;   // 65536 threads = (b, nt16, mc, c)
  int c  = t & 3;
  int mc = (t >> 2) & 31;
  int nt = (t >> 7) & 63;
  int b  = t >> 13;
  uint32_t* dst = adjt + (((size_t)(b * 64 + nt) * 32 + mc) * 128) + c * 32;

  if (bytemode) {
#pragma unroll 4
    for (int l15 = 0; l15 < 16; ++l15) {
      const uint8_t* src = (const uint8_t*)adj +
          ((size_t)(b * 1024 + nt * 16 + l15) * 1024 + mc * 32 + 4 * c);
      uint32_t lo = *(const uint32_t*)src;
      uint32_t hi = *(const uint32_t*)(src + 16);
      dst[2 * l15]     = lo * 0xFFu;
      dst[2 * l15 + 1] = hi * 0xFFu;
    }
  } else {
#pragma unroll 4
    for (int l15 = 0; l15 < 16; ++l15) {
      const uint32_t* src = (const uint32_t*)adj +
          ((size_t)(b * 1024 + nt * 16 + l15) * 1024 + mc * 32 + 4 * c);
      u32x4 qa = *(const u32x4*)src;
      u32x4 qb = *(const u32x4*)(src + 16);
      dst[2 * l15] = (qa[0] ? 0xFFu : 0u) | (qa[1] ? 0xFF00u : 0u) |
                     (qa[2] ? 0xFF0000u : 0u) | (qa[3] ? 0xFF000000u : 0u);
      dst[2 * l15 + 1] = (qb[0] ? 0xFFu : 0u) | (qb[1] ? 0xFF00u : 0u) |
                         (qb[2] ? 0xFF0000u : 0u) | (qb[3] ? 0xFF000000u : 0u);
    }
  }
}

// ---------------------------------------------------------------------------
// Kernel D: per-bh lane-swizzled fp16 pair tables + exact dmax.
// Slot s in [0,512): mc=s>>4, r=s&15, c=r>>2, tt=r&3, q=2c+(tt&1)+8*(tt>>1),
//   m=mc*32+2q: Dsw[bh*512+s]=(half(2^d[m]),half(2^d[m+1])), Esw same with 0.2d.
// In k_attn a lane reads its 4 pair-words with ONE ds_read_b128 per table.
// ---------------------------------------------------------------------------
__global__ __launch_bounds__(256) void k_prep(
    const float* __restrict__ dp, uint32_t* __restrict__ Dsw,
    uint32_t* __restrict__ Esw, float* __restrict__ dmax)
{
  __shared__ float red[4];
  int bh = blockIdx.x, tid = threadIdx.x;
  f32x4 d4 = *(const f32x4*)&dp[bh * 1024 + tid * 4];
  float mx = fmaxf(fmaxf(d4[0], d4[1]), fmaxf(d4[2], d4[3]));
  for (int m = 1; m < 64; m <<= 1) mx = fmaxf(mx, __shfl_xor(mx, m, 64));
  if ((tid & 63) == 0) red[tid >> 6] = mx;
  __syncthreads();
  if (tid == 0) dmax[bh] = fmaxf(fmaxf(red[0], red[1]), fmaxf(red[2], red[3]));

#pragma unroll
  for (int u = 0; u < 2; ++u) {
    int s  = tid * 2 + u;
    int mc = s >> 4, r = s & 15, c = r >> 2, tt = r & 3;
    int q  = 2 * c + (tt & 1) + 8 * (tt >> 1);
    int m  = mc * 32 + 2 * q;
    float da = dp[bh * 1024 + m], db = dp[bh * 1024 + m + 1];
    h2x2 D2; D2[0] = (_Float16)fexp2(da);        D2[1] = (_Float16)fexp2(db);
    h2x2 E2; E2[0] = (_Float16)fexp2(0.2f * da); E2[1] = (_Float16)fexp2(0.2f * db);
    Dsw[bh * 512 + s] = h2bits(D2);
    Esw[bh * 512 + s] = h2bits(E2);
  }
}

// ---------------------------------------------------------------------------
// Kernel W: fragment-arranged w hi/lo planes for both layers (once).
// ---------------------------------------------------------------------------
__global__ __launch_bounds__(256) void k_wprep(
    const float* __restrict__ w0, const float* __restrict__ w1,
    short* __restrict__ wf0h, short* __restrict__ wf0l,
    short* __restrict__ wf1h, short* __restrict__ wf1l)
{
  int t = blockIdx.x * 256 + threadIdx.x;   // 0..8191
  int layer = t >> 12;
  int r = t & 4095;
  int l = r & 63, slot = r >> 6;
  int l15 = l & 15, c = l >> 4;
  int KC  = layer ? 8 : 4;
  int FO  = layer ? 16 : 32;
  int FIN = layer ? 256 : 128;
  int ct  = layer ? (slot >> 3) : (slot >> 2);
  int kc  = layer ? (slot & 7)  : (slot & 3);
  int col = ct * 16 + l15;
  int h   = layer ? (col >> 4) : (col >> 5);
  int o   = col & (FO - 1);
  const float* wp = (layer ? w1 : w0) + (size_t)h * FIN * FO + o;
  short* dh = (layer ? wf1h : wf0h) + (size_t)r * 8;
  short* dl = (layer ? wf1l : wf0l) + (size_t)r * 8;
#pragma unroll
  for (int j = 0; j < 8; j++) {
    int k = kc * 32 + 4 * c + (j & 3) + ((j >> 2) << 4);
    float wv = wp[(size_t)k * FO];
    short hh = f2bf(wv);
    dh[j] = hh;
    dl[j] = f2bf(wv - bf2f(hh));
  }
}

// ---------------------------------------------------------------------------
// Kernel E: emb gather + concat -> xcb bf16 hi/lo planes [8192][128]
// ---------------------------------------------------------------------------
__global__ __launch_bounds__(256) void k_embcat(
    const float* __restrict__ x, const int* __restrict__ verts,
    const float* __restrict__ emb,
    short* __restrict__ xh, short* __restrict__ xl)
{
  int i = blockIdx.x * 256 + threadIdx.x;
  if (i >= 8192 * 64) return;
  int row = i >> 6;
  int c2  = (i & 63) * 2;
  float v0, v1;
  if (c2 < 64) {
    v0 = x[row * 64 + c2];
    v1 = x[row * 64 + c2 + 1];
  } else {
    int v = verts[row];
    v0 = emb[(size_t)v * 64 + (c2 - 64)];
    v1 = emb[(size_t)v * 64 + (c2 - 64) + 1];
  }
  short h0 = f2bf(v0), h1 = f2bf(v1);
  short l0 = f2bf(v0 - bf2f(h0)), l1 = f2bf(v1 - bf2f(h1));
  ((uint32_t*)xh)[i] = (uint32_t)(uint16_t)h0 | ((uint32_t)(uint16_t)h1 << 16);
  ((uint32_t*)xl)[i] = (uint32_t)(uint16_t)l0 | ((uint32_t)(uint16_t)l1 << 16);
}

// ---------------------------------------------------------------------------
// Kernel H: h_prime = xc @ w[h]  (split-bf16, w frags preloaded), tanh -> s,d
// hpb stored FP16, FRAGMENT-ARRANGED: [bh][mc(32)][ctl(CT)][lane(64)][8 f16]
// ---------------------------------------------------------------------------
template<int FIN, int FO>
__global__ __launch_bounds__(256) void k_hprime(
    const short* __restrict__ xcbh, const short* __restrict__ xcbl,
    const short* __restrict__ wfh, const short* __restrict__ wfl,
    const float* __restrict__ a_src, const float* __restrict__ a_dst,
    short* __restrict__ hpbh,
    float* __restrict__ sp, float* __restrict__ dp)
{
  constexpr int CT  = FO / 16;
  constexpr int CTB = 8 * FO / 16;
  constexpr int CTW = CTB / 4;
  constexpr int KC  = FIN / 32;

  int blk = blockIdx.x;              // 512
  int b   = blk >> 6;
  int ntg = blk & 63;
  int tid = threadIdx.x;
  int w4  = tid >> 6;
  int l   = tid & 63;
  int l15 = l & 15, c = l >> 4;

  int row = ntg * 16 + l15;
  const short* arowh = xcbh + ((size_t)(b * 1024 + row)) * FIN;
  const short* arowl = xcbl + ((size_t)(b * 1024 + row)) * FIN;

  f32x4 acc[CTW];
#pragma unroll
  for (int i = 0; i < CTW; i++) acc[i] = (f32x4){0.f, 0.f, 0.f, 0.f};

  for (int kc = 0; kc < KC; ++kc) {
    s16x4 ah0 = *(const s16x4*)(arowh + kc * 32 + 4 * c);
    s16x4 ah1 = *(const s16x4*)(arowh + kc * 32 + 4 * c + 16);
    s16x4 al0 = *(const s16x4*)(arowl + kc * 32 + 4 * c);
    s16x4 al1 = *(const s16x4*)(arowl + kc * 32 + 4 * c + 16);
    s16x8 afh, afl;
#pragma unroll
    for (int j = 0; j < 4; j++) {
      afh[j] = ah0[j]; afh[4 + j] = ah1[j];
      afl[j] = al0[j]; afl[4 + j] = al1[j];
    }
#pragma unroll
    for (int i = 0; i < CTW; i++) {
      int ct = w4 * CTW + i;
      s16x8 bfh = *(const s16x8*)(wfh + ((size_t)(ct * KC + kc) * 64 + l) * 8);
      s16x8 bfl = *(const s16x8*)(wfl + ((size_t)(ct * KC + kc) * 64 + l) * 8);
      acc[i] = __builtin_amdgcn_mfma_f32_16x16x32_bf16(afh, bfh, acc[i], 0, 0, 0);
      acc[i] = __builtin_amdgcn_mfma_f32_16x16x32_bf16(afl, bfh, acc[i], 0, 0, 0);
      acc[i] = __builtin_amdgcn_mfma_f32_16x16x32_bf16(afh, bfl, acc[i], 0, 0, 0);
    }
  }

  float s_acc[CTW][4];
  float d_acc[CTW][4];
#pragma unroll
  for (int i = 0; i < CTW; i++) {
    int ct  = w4 * CTW + i;
    int col = ct * 16 + l15;
    int h = col / FO, o = col % FO;
    float asv = a_src[h * FO + o];
    float adv = a_dst[h * FO + o];
    s16x4 hbh;
#pragma unroll
    for (int r = 0; r < 4; r++) {
      float hp = acc[i][r];
      union { _Float16 f; short s; } cv;
      cv.f = (_Float16)hp;
      hbh[r] = cv.s;
      float t = ftanh(hp);
      s_acc[i][r] = t * asv;
      d_acc[i][r] = t * adv;
    }
    int bh  = b * 8 + h;
    int ctl = o >> 4;
    size_t off = ((((size_t)(bh * 32 + (ntg >> 1))) * CT + ctl) * 64 + l) * 16 + (size_t)(ntg & 1) * 8;
    *(s16x4*)((char*)hpbh + off) = hbh;
  }

  constexpr int HW = (CTW * 16) / FO;
#pragma unroll
  for (int hh = 0; hh < HW; ++hh) {
#pragma unroll
    for (int r = 0; r < 4; r++) {
      float sv = 0.f, dv = 0.f;
#pragma unroll
      for (int i = hh * CT; i < (hh + 1) * CT; ++i) { sv += s_acc[i][r]; dv += d_acc[i][r]; }
      for (int m = 1; m < 16; m <<= 1) {
        sv += __shfl_xor(sv, m, 64);
        dv += __shfl_xor(dv, m, 64);
      }
      if (l15 == 0) {
        int ct0 = w4 * CTW + hh * CT;
        int h   = (ct0 * 16) / FO;
        int bh  = b * 8 + h;
        int rn  = ntg * 16 + 4 * c + r;
        sp[bh * 1024 + rn] = sv * LOG2E;
        dp[bh * 1024 + rn] = dv * LOG2E;
      }
    }
  }
}

// ---------------------------------------------------------------------------
// Kernel A: masked softmax(leaky(s+d)) @ h_prime — packed-fp16 score path.
//   p2 = max(cA2*D2, cB2*E2)  (v_pk_mul_f16 / v_pk_max_f16) — result IS the
//   MFMA half-word. P scaled by 256 (cancels in softmax) vs fp16 underflow.
//   adj: one coalesced dwordx2/iter. Row sums via f16 MFMA vs ones.
// ---------------------------------------------------------------------------
template<int CT, bool IS_L0>
__global__ __launch_bounds__(512, 8) void k_attn(
    const float* __restrict__ sp, const uint32_t* __restrict__ Dsw,
    const uint32_t* __restrict__ Esw, const float* __restrict__ dmax,
    const short* __restrict__ hpbh,
    const uint32_t* __restrict__ adjt,
    const float* __restrict__ bias,
    void* __restrict__ outh, void* __restrict__ outl)
{
  __shared__ uint32_t Dl[512];
  __shared__ uint32_t El[512];
  __shared__ float racc[4][(CT + 1) * 4][64];

  int i0   = blockIdx.x;          // 1024
  int xcd  = i0 & 7, slot = i0 >> 3;
  int bh   = xcd * 8 + (slot >> 4);
  int rb   = (slot & 15) * 64;
  int b    = bh >> 3;
  int tid  = threadIdx.x;
  int wid  = tid >> 6;            // 0..7
  int r16  = wid >> 1;            // row tile
  int half = wid & 1;             // mc half
  int l = tid & 63, l15 = l & 15, c = l >> 4;

  if (tid < 512) {
    Dl[tid] = Dsw[bh * 512 + tid];
    El[tid] = Esw[bh * 512 + tid];
  }

  float maxd = dmax[bh];
  int n = rb + r16 * 16 + l15;
  float svn = sp[bh * 1024 + n];
  float su  = svn + maxd;
  float ub  = fmaxf(su, 0.2f * su);      // >= true row max (leaky monotone)
  float cAf = fexp2(svn - ub + 8.0f);          // x256
  float cBf = fexp2(0.2f * svn - ub + 8.0f);   // x256
  h2x2 cA2; cA2[0] = (_Float16)cAf; cA2[1] = (_Float16)cAf;
  h2x2 cB2; cB2[0] = (_Float16)cBf; cB2[1] = (_Float16)cBf;
  const short* hpbase = hpbh + (size_t)bh * 32 * CT * 512;
  const uint32_t* atile = adjt + ((size_t)(b * 64 + (rb >> 4) + r16) * 32) * 128 + l * 2;

  __syncthreads();

  f32x4 acc[CT];
#pragma unroll
  for (int i = 0; i < CT; i++) acc[i] = (f32x4){0.f, 0.f, 0.f, 0.f};
  f32x4 accp = (f32x4){0.f, 0.f, 0.f, 0.f};
  union { s16x8 s; f16x8 f; } ones;
#pragma unroll
  for (int j = 0; j < 8; j++) ones.s[j] = (short)0x3C00;   // fp16 1.0

  const int mcBeg = half * 16;
  // distance-1 staging
  u32x2 nam = *(const u32x2*)(atile + (size_t)mcBeg * 128);
  s16x8 nb[CT];
#pragma unroll
  for (int i = 0; i < CT; i++)
    nb[i] = *(const s16x8*)(hpbase + ((size_t)(mcBeg * CT + i) * 64 + l) * 8);

  for (int t = 0; t < 16; ++t) {
    int mc = mcBeg + t;
    u32x2 am = nam;
    union { s16x8 s; f16x8 f; } cb[CT];
#pragma unroll
    for (int i = 0; i < CT; i++) cb[i].s = nb[i];
    if (t < 15) {
      int mcn = mc + 1;
      nam = *(const u32x2*)(atile + (size_t)mcn * 128);
#pragma unroll
      for (int i = 0; i < CT; i++)
        nb[i] = *(const s16x8*)(hpbase + ((size_t)(mcn * CT + i) * 64 + l) * 8);
    }

    u32x4 dq = *(const u32x4*)&Dl[mc * 16 + 4 * c];
    u32x4 eq = *(const u32x4*)&El[mc * 16 + 4 * c];

    union { u32x4 w; s16x8 s; f16x8 f; } pu;
#pragma unroll
    for (int tt = 0; tt < 4; ++tt) {
      h2x2 p2 = __builtin_elementwise_max(cA2 * bits2h(dq[tt]), cB2 * bits2h(eq[tt]));
      uint32_t msk = __builtin_amdgcn_perm(0u, am[tt >> 1],
                                           (tt & 1) ? 0x03030202u : 0x01010000u);
      pu.w[tt] = h2bits(p2) & msk;
    }

#pragma unroll
    for (int i = 0; i < CT; i++)
      acc[i] = __builtin_amdgcn_mfma_f32_16x16x32_f16(pu.f, cb[i].f, acc[i], 0, 0, 0);
    accp = __builtin_amdgcn_mfma_f32_16x16x32_f16(pu.f, ones.f, accp, 0, 0, 0);
  }

  // pair-reduce the two mc-halves
  if (half == 1) {
#pragma unroll
    for (int i = 0; i < CT; i++)
#pragma unroll
      for (int r = 0; r < 4; r++) racc[r16][i * 4 + r][l] = acc[i][r];
#pragma unroll
    for (int r = 0; r < 4; r++) racc[r16][CT * 4 + r][l] = accp[r];
  }
  __syncthreads();
  if (half == 0) {
#pragma unroll
    for (int i = 0; i < CT; i++)
#pragma unroll
      for (int r = 0; r < 4; r++) acc[i][r] += racc[r16][i * 4 + r][l];
#pragma unroll
    for (int r = 0; r < 4; r++) {
      float rs  = accp[r] + racc[r16][CT * 4 + r][l];
      float inv = frcp(rs);
      int rown  = rb + r16 * 16 + 4 * c + r;
#pragma unroll
      for (int i = 0; i < CT; i++) {
        float v = acc[i][r] * inv;
        int col = i * 16 + l15;
        int h   = bh & 7;
        if (IS_L0) {
          v += bias[col];
          v = v > 0.f ? v : fexp2(v * LOG2E) - 1.f;   // elu
          size_t idx = ((size_t)(b * 1024 + rown)) * 256 + h * 32 + col;
          short vh = f2bf(v);
          ((short*)outh)[idx] = vh;
          ((short*)outl)[idx] = f2bf(v - bf2f(vh));
        } else {
          ((float*)outh)[(((size_t)(b * 8 + h)) * 1024 + rown) * 16 + col] = v;
        }
      }
    }
  }
}

// ---------------------------------------------------------------------------
// Kernel F: mean over heads + bias + log_softmax(16)
// ---------------------------------------------------------------------------
__global__ __launch_bounds__(256) void k_final(
    const float* __restrict__ out1, const float* __restrict__ b1,
    float* __restrict__ out)
{
  int idx = blockIdx.x * 256 + threadIdx.x;
  if (idx >= 8192) return;
  int b = idx >> 10, n = idx & 1023;
  float v[16];
#pragma unroll
  for (int o = 0; o < 16; o++) v[o] = 0.f;
  for (int h = 0; h < 8; h++) {
    const float* p = out1 + (((size_t)(b * 8 + h)) * 1024 + n) * 16;
#pragma unroll
    for (int o = 0; o < 16; o++) v[o] += p[o];
  }
  float mx = -1e30f;
#pragma unroll
  for (int o = 0; o < 16; o++) {
    v[o] = v[o] * 0.125f + b1[o];
    mx = fmaxf(mx, v[o]);
  }
  float s = 0.f;
#pragma unroll
  for (int o = 0; o < 16; o++) s += fexp2((v[o] - mx) * LOG2E);
  float lse = flog2(s) * LN2;
#pragma unroll
  for (int o = 0; o < 16; o++) out[(size_t)idx * 16 + o] = v[o] - mx - lse;
}

// ---------------------------------------------------------------------------
extern "C" void kernel_launch(void* const* d_in, const int* in_sizes, int n_in,
                              void* d_out, int out_size, void* d_ws, size_t ws_size,
                              hipStream_t stream) {
  const float*   x     = (const float*)d_in[0];
  const int*     verts = (const int*)d_in[1];
  const void*    adj   = (const void*)d_in[2];   // int32 or uint8 — auto-detected
  const float*   emb   = (const float*)d_in[3];
  const float*   w0    = (const float*)d_in[4];
  const float*   as0   = (const float*)d_in[5];
  const float*   ad0   = (const float*)d_in[6];
  const float*   b0    = (const float*)d_in[7];
  const float*   w1    = (const float*)d_in[8];
  const float*   as1   = (const float*)d_in[9];
  const float*   ad1   = (const float*)d_in[10];
  const float*   b1    = (const float*)d_in[11];

  char* ws = (char*)d_ws;
  const size_t MB = 1ull << 20;
  short* xcbh  = (short*)(ws);                         // 2 MB
  short* xcbl  = (short*)(ws + 2 * MB);                // 2 MB
  short* hpb0h = (short*)(ws + 4 * MB);                // 4 MB (dead after attn0)
  float* out1  = (float*)(ws + 4 * MB);                // 4 MB (reuses hpb0h)
  float* s0    = (float*)(ws + 8 * MB);                // 256 KB
  float* d0    = (float*)(ws + 8 * MB + 256 * 1024);   // 256 KB
  short* x1h   = (short*)(ws + 8 * MB + 512 * 1024);   // 4 MB
  short* x1l   = (short*)(ws + 12 * MB + 512 * 1024);  // 4 MB
  short* hpb1h = (short*)(ws + 16 * MB + 512 * 1024);  // 2 MB
  float* s1    = (float*)(ws + 18 * MB + 512 * 1024);  // 256 KB
  float* d1    = (float*)(ws + 18 * MB + 768 * 1024);  // 256 KB
  uint32_t* adjt = (uint32_t*)(ws + 19 * MB);          // 8 MB
  short* wf0h  = (short*)(ws + 27 * MB);               // 64 KB each
  short* wf0l  = (short*)(ws + 27 * MB + 64 * 1024);
  short* wf1h  = (short*)(ws + 27 * MB + 128 * 1024);
  short* wf1l  = (short*)(ws + 27 * MB + 192 * 1024);
  uint32_t* Dsw  = (uint32_t*)(ws + 27 * MB + 256 * 1024);  // 128 KB
  uint32_t* Esw  = (uint32_t*)(ws + 27 * MB + 384 * 1024);  // 128 KB
  float*    dmax = (float*)(ws + 27 * MB + 512 * 1024);     // 256 B
  float* out   = (float*)d_out;

  k_adjperm<<<256, 256, 0, stream>>>(adj, adjt);
  k_wprep<<<32, 256, 0, stream>>>(w0, w1, wf0h, wf0l, wf1h, wf1l);
  k_embcat<<<2048, 256, 0, stream>>>(x, verts, emb, xcbh, xcbl);
  k_hprime<128, 32><<<512, 256, 0, stream>>>(xcbh, xcbl, wf0h, wf0l, as0, ad0, hpb0h, s0, d0);
  k_prep<<<64, 256, 0, stream>>>(d0, Dsw, Esw, dmax);
  k_attn<2, true><<<1024, 512, 0, stream>>>(s0, Dsw, Esw, dmax, hpb0h, adjt, b0, (void*)x1h, (void*)x1l);
  k_hprime<256, 16><<<512, 256, 0, stream>>>(x1h, x1l, wf1h, wf1l, as1, ad1, hpb1h, s1, d1);
  k_prep<<<64, 256, 0, stream>>>(d1, Dsw, Esw, dmax);
  k_attn<1, false><<<1024, 512, 0, stream>>>(s1, Dsw, Esw, dmax, hpb1h, adjt, b1, (void*)out1, nullptr);
  k_final<<<32, 256, 0, stream>>>(out1, b1, out);
}